// Round 2
// baseline (264.873 us; speedup 1.0000x reference)
//
#include <hip/hip_runtime.h>
#include <stdint.h>

typedef short v8s __attribute__((ext_vector_type(8)));
typedef float v4f __attribute__((ext_vector_type(4)));

#define AS1 __attribute__((address_space(1)))
#define AS3 __attribute__((address_space(3)))

__device__ __forceinline__ void glds16(const void* g, void* l) {
  __builtin_amdgcn_global_load_lds((const AS1 void*)g, (AS3 void*)l, 16, 0, 0);
}

__device__ __forceinline__ short f2bf(float f) {
  uint32_t u = __float_as_uint(f);
  u += 0x7fffu + ((u >> 16) & 1u);   // RNE; inputs are finite
  return (short)(u >> 16);
}

__device__ __forceinline__ float bf2f(short s) {
  uint32_t u = ((uint32_t)(uint16_t)s) << 16;
  return __uint_as_float(u);
}

// ---------------- prep kernels ----------------

__global__ __launch_bounds__(256) void cast_f32_bf16(const float* __restrict__ in,
                                                     short* __restrict__ out, int n4) {
  int i = blockIdx.x * 256 + threadIdx.x;
  if (i < n4) {
    float4 v = ((const float4*)in)[i];
    short4 o = { f2bf(v.x), f2bf(v.y), f2bf(v.z), f2bf(v.w) };
    ((short4*)out)[i] = o;
  }
}

// in: Z slices of RxC fp32 row-major; out: Z slices of CxR bf16 row-major (out[c][r]=in[r][c])
__global__ __launch_bounds__(256) void transpose_cast(const float* __restrict__ in,
                                                      short* __restrict__ out, int R, int C) {
  __shared__ float tile[64][65];
  size_t sl = (size_t)blockIdx.z * R * C;
  in += sl; out += sl;
  int rb = blockIdx.x * 64, cb = blockIdx.y * 64;
  int t = threadIdx.x;
  int col = t & 63, r0 = t >> 6;
#pragma unroll
  for (int i = 0; i < 16; ++i) {
    int row = r0 + i * 4;
    tile[row][col] = in[(size_t)(rb + row) * C + cb + col];
  }
  __syncthreads();
#pragma unroll
  for (int i = 0; i < 16; ++i) {
    int orow = r0 + i * 4;
    out[(size_t)(cb + orow) * R + rb + col] = f2bf(tile[col][orow]);
  }
}

// ---------------- 128x128 GEMM core (m97 structure) ----------------
// A: [M x 1024] bf16 row-major (tile rows at Ag), Bt: [N x 1024] bf16 row-major (B^T).
// acc[mt][nt] rows = wr+mt*16+quad*4+r, cols = wc+nt*16+(lane&15).
__device__ __forceinline__ void gemm_core128(const short* __restrict__ Ag,
                                             const short* __restrict__ Bg,
                                             short* As, short* Bs,
                                             v4f (&acc)[4][4]) {
  const int tid  = threadIdx.x;
  const int lane = tid & 63;
  const int w    = tid >> 6;
  const int quad = lane >> 4;
  const int c15  = lane & 15;
  const int wr   = (w >> 1) * 64;
  const int wc   = (w & 1) * 64;

  // staging: chunk c -> row=c>>2, 16B part=c&3 ; LDS slot = c*16B  (layout [row][32])
  const int r0 = tid >> 2, p0 = tid & 3;
  const short* g0 = Ag + (size_t)r0 * 1024 + p0 * 8;
  const short* g1 = g0 + 64 * 1024;
  const short* h0 = Bg + (size_t)r0 * 1024 + p0 * 8;
  const short* h1 = h0 + 64 * 1024;
  short* lA0 = As + tid * 8;
  short* lA1 = As + (256 + tid) * 8;
  short* lB0 = Bs + tid * 8;
  short* lB1 = Bs + (256 + tid) * 8;

  for (int kb = 0; kb < 32; ++kb) {
    __syncthreads();                 // previous tile fully consumed
    glds16(g0, lA0); glds16(g1, lA1);
    glds16(h0, lB0); glds16(h1, lB1);
    g0 += 32; g1 += 32; h0 += 32; h1 += 32;
    __syncthreads();                 // vmcnt(0) drain + barrier

    v8s a[4], b[4];
#pragma unroll
    for (int mt = 0; mt < 4; ++mt)
      a[mt] = *(const v8s*)(As + (wr + mt * 16 + c15) * 32 + quad * 8);
#pragma unroll
    for (int nt = 0; nt < 4; ++nt)
      b[nt] = *(const v8s*)(Bs + (wc + nt * 16 + c15) * 32 + quad * 8);
#pragma unroll
    for (int mt = 0; mt < 4; ++mt)
#pragma unroll
      for (int nt = 0; nt < 4; ++nt)
        acc[mt][nt] = __builtin_amdgcn_mfma_f32_16x16x32_bf16(a[mt], b[nt], acc[mt][nt], 0, 0, 0);
  }
}

// ---------------- QKV projection ----------------
// z=0: Q -> Qb [b,h,s,e]; z=1: K -> Kb [b,h,s,e]; z=2: V -> Vtb [b,h,e,s] (transposed)
__global__ __launch_bounds__(256, 2) void proj_gemm(
    const short* __restrict__ xQ, const short* __restrict__ xK, const short* __restrict__ xV,
    const short* __restrict__ WqT, const short* __restrict__ WkT, const short* __restrict__ WvT,
    const float* __restrict__ bq, const float* __restrict__ bk, const float* __restrict__ bv,
    short* __restrict__ Qb, short* __restrict__ Kb, short* __restrict__ Vtb) {
  __shared__ short As[4096];
  __shared__ short Bs[4096];
  const int z = blockIdx.z;
  const short* A    = (z == 0) ? xQ  : (z == 1) ? xK  : xV;
  const short* Bt   = (z == 0) ? WqT : (z == 1) ? WkT : WvT;
  const float* bias = (z == 0) ? bq  : (z == 1) ? bk  : bv;
  short* outp       = (z == 0) ? Qb  : (z == 1) ? Kb  : Vtb;
  const int mb = blockIdx.y * 128, nb = blockIdx.x * 128;
  v4f acc[4][4] = {};
  gemm_core128(A + (size_t)mb * 1024, Bt + (size_t)nb * 1024, As, Bs, acc);

  const int lane = threadIdx.x & 63, w = threadIdx.x >> 6;
  const int quad = lane >> 4, c15 = lane & 15;
  const int wr = (w >> 1) * 64, wc = (w & 1) * 64;
  const bool vmode = (z == 2);
#pragma unroll
  for (int nt = 0; nt < 4; ++nt) {
    const int gn = nb + wc + nt * 16 + c15;
    const float bb = bias[gn];
    const int h = gn >> 6, e = gn & 63;
#pragma unroll
    for (int mt = 0; mt < 4; ++mt) {
#pragma unroll
      for (int r = 0; r < 4; ++r) {
        const int gm = mb + wr + mt * 16 + quad * 4 + r;
        const int bi = gm >> 10, s = gm & 1023;
        const float v = acc[mt][nt][r] + bb;
        const size_t base = (size_t)(bi * 16 + h) * 65536;
        if (!vmode) outp[base + (size_t)s * 64 + e]   = f2bf(v);
        else        outp[base + (size_t)e * 1024 + s] = f2bf(v);
      }
    }
  }
}

// ---------------- output projection ----------------
__global__ __launch_bounds__(256, 2) void out_gemm(
    const short* __restrict__ AV, const short* __restrict__ WoT,
    const float* __restrict__ bo, float* __restrict__ outp) {
  __shared__ short As[4096];
  __shared__ short Bs[4096];
  const int mb = blockIdx.y * 128, nb = blockIdx.x * 128;
  v4f acc[4][4] = {};
  gemm_core128(AV + (size_t)mb * 1024, WoT + (size_t)nb * 1024, As, Bs, acc);
  const int lane = threadIdx.x & 63, w = threadIdx.x >> 6;
  const int quad = lane >> 4, c15 = lane & 15;
  const int wr = (w >> 1) * 64, wc = (w & 1) * 64;
#pragma unroll
  for (int nt = 0; nt < 4; ++nt) {
    const int gn = nb + wc + nt * 16 + c15;
    const float bb = bo[gn];
#pragma unroll
    for (int mt = 0; mt < 4; ++mt)
#pragma unroll
      for (int r = 0; r < 4; ++r) {
        const int gm = mb + wr + mt * 16 + quad * 4 + r;
        outp[(size_t)gm * 1024 + gn] = acc[mt][nt][r] + bb;
      }
  }
}

// ---------------- flash attention ----------------
// grid (S/64, H, B); 4 waves, wave w owns query rows qb*64+w*16 .. +15.
__global__ __launch_bounds__(256, 2) void attn_kernel(
    const short* __restrict__ Qb, const short* __restrict__ Kb,
    const short* __restrict__ Vtb, const int* __restrict__ lens,
    short* __restrict__ AVb) {
  __shared__ short Ksm[64 * 72];      // [key][dh], stride 72 (pad kills 128B-stride degeneracy)
  __shared__ short Vsm[64 * 72];      // [dh][key]
  __shared__ short Psm[4 * 1152];     // per-wave [16][72]
  const int tid = threadIdx.x, lane = tid & 63, w = tid >> 6;
  const int quad = lane >> 4, c15 = lane & 15;
  const int qb = blockIdx.x, h = blockIdx.y, b = blockIdx.z;
  const int bh = b * 16 + h;
  const short* Qp = Qb  + (size_t)bh * 65536;
  const short* Kp = Kb  + (size_t)bh * 65536;
  const short* Vp = Vtb + (size_t)bh * 65536;
  const int len = lens[b];

  v8s aq[2];
  const int qrow = qb * 64 + w * 16 + c15;
#pragma unroll
  for (int kf = 0; kf < 2; ++kf)
    aq[kf] = *(const v8s*)(Qp + (size_t)qrow * 64 + kf * 32 + quad * 8);

  // query-row mask folded with 1/sqrt(64); masked rows -> scores 0 -> uniform softmax (matches ref)
  float mrow[4];
#pragma unroll
  for (int r = 0; r < 4; ++r) {
    int sg = qb * 64 + w * 16 + quad * 4 + r;
    mrow[r] = (sg < len) ? 0.125f : 0.0f;
  }

  float m_run[4] = { -3e38f, -3e38f, -3e38f, -3e38f };
  float l_run[4] = { 0.f, 0.f, 0.f, 0.f };
  v4f o[4] = {};

  // staging: 64 rows x 64 shorts (128 B) per block = 8192 B for K and for V.
  // 256 threads x 2 x 16 B each: parts spart and spart+4 of each row.
  const int srow = tid >> 2, spart = tid & 3;
  const short* kg = Kp + (size_t)srow * 64 + spart * 8;     // +32 for second half
  const short* vg = Vp + (size_t)srow * 1024 + spart * 8;   // +32 for second half
  short* lK = Ksm + srow * 72 + spart * 8;
  short* lV = Vsm + srow * 72 + spart * 8;
  short* Pw = Psm + w * 1152;

  for (int kb = 0; kb < 16; ++kb) {
    __syncthreads();
    v8s k0 = *(const v8s*)kg;
    v8s k1 = *(const v8s*)(kg + 32);
    v8s v0 = *(const v8s*)vg;
    v8s v1 = *(const v8s*)(vg + 32);
    *(v8s*)lK = k0;
    *(v8s*)(lK + 32) = k1;
    *(v8s*)lV = v0;
    *(v8s*)(lV + 32) = v1;
    kg += 4096; vg += 64;
    __syncthreads();

    // S = Q K^T (16 x 64 per wave)
    v4f sc[4] = {};
#pragma unroll
    for (int nt = 0; nt < 4; ++nt)
#pragma unroll
      for (int kf = 0; kf < 2; ++kf) {
        v8s bk_ = *(const v8s*)(Ksm + (nt * 16 + c15) * 72 + kf * 32 + quad * 8);
        sc[nt] = __builtin_amdgcn_mfma_f32_16x16x32_bf16(aq[kf], bk_, sc[nt], 0, 0, 0);
      }
#pragma unroll
    for (int nt = 0; nt < 4; ++nt)
#pragma unroll
      for (int r = 0; r < 4; ++r) sc[nt][r] *= mrow[r];

    // online softmax: row = quad*4+r lives in this quad's 16 lanes
    float mx[4];
#pragma unroll
    for (int r = 0; r < 4; ++r)
      mx[r] = fmaxf(fmaxf(sc[0][r], sc[1][r]), fmaxf(sc[2][r], sc[3][r]));
#pragma unroll
    for (int d = 1; d < 16; d <<= 1)
#pragma unroll
      for (int r = 0; r < 4; ++r) mx[r] = fmaxf(mx[r], __shfl_xor(mx[r], d));

    float al[4];
#pragma unroll
    for (int r = 0; r < 4; ++r) {
      float mn = fmaxf(m_run[r], mx[r]);
      al[r] = __expf(m_run[r] - mn);
      m_run[r] = mn;
    }
    // p rounded to bf16 FIRST; denominator sums the rounded values so the
    // softmax numerator (bf16 P into MFMA) and denominator match exactly.
    short pb[4][4];
    float sm[4] = { 0.f, 0.f, 0.f, 0.f };
#pragma unroll
    for (int nt = 0; nt < 4; ++nt)
#pragma unroll
      for (int r = 0; r < 4; ++r) {
        short q = f2bf(__expf(sc[nt][r] - m_run[r]));
        pb[nt][r] = q;
        sm[r] += bf2f(q);
      }
#pragma unroll
    for (int d = 1; d < 16; d <<= 1)
#pragma unroll
      for (int r = 0; r < 4; ++r) sm[r] += __shfl_xor(sm[r], d);
#pragma unroll
    for (int r = 0; r < 4; ++r) l_run[r] = l_run[r] * al[r] + sm[r];
#pragma unroll
    for (int t = 0; t < 4; ++t)
#pragma unroll
      for (int r = 0; r < 4; ++r) o[t][r] *= al[r];

    // P: C/D layout -> A-operand layout via per-wave LDS (m120-verified transform)
#pragma unroll
    for (int nt = 0; nt < 4; ++nt)
#pragma unroll
      for (int r = 0; r < 4; ++r)
        Pw[(quad * 4 + r) * 72 + nt * 16 + c15] = pb[nt][r];
    __builtin_amdgcn_s_waitcnt(0xc07f);   // lgkmcnt(0); per-wave region, no barrier needed

    // O += P V
#pragma unroll
    for (int kf = 0; kf < 2; ++kf) {
      v8s pa = *(const v8s*)(Pw + c15 * 72 + kf * 32 + quad * 8);
#pragma unroll
      for (int t = 0; t < 4; ++t) {
        v8s vb = *(const v8s*)(Vsm + (t * 16 + c15) * 72 + kf * 32 + quad * 8);
        o[t] = __builtin_amdgcn_mfma_f32_16x16x32_bf16(pa, vb, o[t], 0, 0, 0);
      }
    }
  }

  float inv[4];
#pragma unroll
  for (int r = 0; r < 4; ++r) inv[r] = 1.0f / l_run[r];
#pragma unroll
  for (int t = 0; t < 4; ++t)
#pragma unroll
    for (int r = 0; r < 4; ++r) {
      int sg = qb * 64 + w * 16 + quad * 4 + r;
      AVb[(size_t)(b * 1024 + sg) * 1024 + h * 64 + t * 16 + c15] = f2bf(o[t][r] * inv[r]);
    }
}

// ---------------- launch ----------------
extern "C" void kernel_launch(void* const* d_in, const int* in_sizes, int n_in,
                              void* d_out, int out_size, void* d_ws, size_t ws_size,
                              hipStream_t stream) {
  const float* xQ = (const float*)d_in[0];
  const float* xK = (const float*)d_in[1];
  const float* xV = (const float*)d_in[2];
  const int* lens = (const int*)d_in[3];
  const float* Wq = (const float*)d_in[4];
  const float* bq = (const float*)d_in[5];
  const float* Wk = (const float*)d_in[6];
  const float* bk = (const float*)d_in[7];
  const float* Wv = (const float*)d_in[8];
  const float* bv = (const float*)d_in[9];
  const float* Wo = (const float*)d_in[10];
  const float* bo = (const float*)d_in[11];
  float* out = (float*)d_out;

  char* ws = (char*)d_ws;
  short* xQb = (short*)(ws + 0);                 // 8 MB  [4096][1024] bf16
  short* xKb = (short*)(ws + 8388608);
  short* xVb = (short*)(ws + 16777216);
  short* WqT = (short*)(ws + 25165824);          // 2 MB  [n=h*64+e][d]
  short* WkT = (short*)(ws + 27262976);
  short* WvT = (short*)(ws + 29360128);
  short* WoT = (short*)(ws + 31457280);          // 2 MB  Wo^T [n][k]
  short* Qb  = (short*)(ws + 33554432);          // 8 MB  [b,h,s,e]
  short* Kb  = (short*)(ws + 41943040);          // 8 MB  [b,h,s,e]
  short* Vtb = (short*)(ws + 50331648);          // 8 MB  [b,h,e,s]
  short* AVb = (short*)(ws + 58720256);          // 8 MB  [b,s,h*64+e]

  cast_f32_bf16<<<4096, 256, 0, stream>>>(xQ, xQb, 1048576);
  cast_f32_bf16<<<4096, 256, 0, stream>>>(xK, xKb, 1048576);
  cast_f32_bf16<<<4096, 256, 0, stream>>>(xV, xVb, 1048576);
  transpose_cast<<<dim3(16, 1, 16), 256, 0, stream>>>(Wq, WqT, 1024, 64);
  transpose_cast<<<dim3(16, 1, 16), 256, 0, stream>>>(Wk, WkT, 1024, 64);
  transpose_cast<<<dim3(16, 1, 16), 256, 0, stream>>>(Wv, WvT, 1024, 64);
  transpose_cast<<<dim3(16, 16, 1), 256, 0, stream>>>(Wo, WoT, 1024, 1024);
  proj_gemm<<<dim3(8, 32, 3), 256, 0, stream>>>(xQb, xKb, xVb, WqT, WkT, WvT,
                                                bq, bk, bv, Qb, Kb, Vtb);
  attn_kernel<<<dim3(16, 16, 4), 256, 0, stream>>>(Qb, Kb, Vtb, lens, AVb);
  out_gemm<<<dim3(8, 32, 1), 256, 0, stream>>>(AVb, WoT, bo, out);
}

// Round 3
// 253.372 us; speedup vs baseline: 1.0454x; 1.0454x over previous
//
#include <hip/hip_runtime.h>
#include <stdint.h>

typedef short v8s __attribute__((ext_vector_type(8)));
typedef float v4f __attribute__((ext_vector_type(4)));

#define AS1 __attribute__((address_space(1)))
#define AS3 __attribute__((address_space(3)))

__device__ __forceinline__ void glds16(const void* g, void* l) {
  __builtin_amdgcn_global_load_lds((const AS1 void*)g, (AS3 void*)l, 16, 0, 0);
}

__device__ __forceinline__ short f2bf(float f) {
  uint32_t u = __float_as_uint(f);
  u += 0x7fffu + ((u >> 16) & 1u);   // RNE; inputs are finite
  return (short)(u >> 16);
}

// ---------------- prep kernels ----------------

// z selects which of the three tensors to cast
__global__ __launch_bounds__(256) void cast3_f32_bf16(
    const float* __restrict__ a, const float* __restrict__ b, const float* __restrict__ c,
    short* __restrict__ oa, short* __restrict__ ob, short* __restrict__ oc, int n4) {
  const float* in = (blockIdx.z == 0) ? a : (blockIdx.z == 1) ? b : c;
  short* out      = (blockIdx.z == 0) ? oa : (blockIdx.z == 1) ? ob : oc;
  int i = blockIdx.x * 256 + threadIdx.x;
  if (i < n4) {
    float4 v = ((const float4*)in)[i];
    short4 o = { f2bf(v.x), f2bf(v.y), f2bf(v.z), f2bf(v.w) };
    ((short4*)out)[i] = o;
  }
}

// in: Z slices of RxC fp32 row-major; out: Z slices of CxR bf16 row-major (out[c][r]=in[r][c])
__global__ __launch_bounds__(256) void transpose_cast(const float* __restrict__ in,
                                                      short* __restrict__ out, int R, int C) {
  __shared__ float tile[64][65];
  size_t sl = (size_t)blockIdx.z * R * C;
  in += sl; out += sl;
  int rb = blockIdx.x * 64, cb = blockIdx.y * 64;
  int t = threadIdx.x;
  int col = t & 63, r0 = t >> 6;
#pragma unroll
  for (int i = 0; i < 16; ++i) {
    int row = r0 + i * 4;
    tile[row][col] = in[(size_t)(rb + row) * C + cb + col];
  }
  __syncthreads();
#pragma unroll
  for (int i = 0; i < 16; ++i) {
    int orow = r0 + i * 4;
    out[(size_t)(cb + orow) * R + rb + col] = f2bf(tile[col][orow]);
  }
}

// fused per-head W transposes for Wq/Wk/Wv: z/16 picks tensor, z%16 the head slice
__global__ __launch_bounds__(256) void transpose_cast_w3(
    const float* __restrict__ wq, const float* __restrict__ wk, const float* __restrict__ wv,
    short* __restrict__ oq, short* __restrict__ ok, short* __restrict__ ov) {
  __shared__ float tile[64][65];
  const int which = blockIdx.z >> 4, slice = blockIdx.z & 15;
  const float* in = (which == 0) ? wq : (which == 1) ? wk : wv;
  short* out      = (which == 0) ? oq : (which == 1) ? ok : ov;
  const int R = 1024, C = 64;
  in  += (size_t)slice * R * C;
  out += (size_t)slice * R * C;
  int rb = blockIdx.x * 64;
  int t = threadIdx.x;
  int col = t & 63, r0 = t >> 6;
#pragma unroll
  for (int i = 0; i < 16; ++i) {
    int row = r0 + i * 4;
    tile[row][col] = in[(size_t)(rb + row) * C + col];
  }
  __syncthreads();
#pragma unroll
  for (int i = 0; i < 16; ++i) {
    int orow = r0 + i * 4;
    out[(size_t)orow * R + rb + col] = f2bf(tile[col][orow]);
  }
}

// ---------------- 128x128 GEMM core (m97 structure) ----------------
__device__ __forceinline__ void gemm_core128(const short* __restrict__ Ag,
                                             const short* __restrict__ Bg,
                                             short* As, short* Bs,
                                             v4f (&acc)[4][4]) {
  const int tid  = threadIdx.x;
  const int lane = tid & 63;
  const int w    = tid >> 6;
  const int quad = lane >> 4;
  const int c15  = lane & 15;
  const int wr   = (w >> 1) * 64;
  const int wc   = (w & 1) * 64;

  const int r0 = tid >> 2, p0 = tid & 3;
  const short* g0 = Ag + (size_t)r0 * 1024 + p0 * 8;
  const short* g1 = g0 + 64 * 1024;
  const short* h0 = Bg + (size_t)r0 * 1024 + p0 * 8;
  const short* h1 = h0 + 64 * 1024;
  short* lA0 = As + tid * 8;
  short* lA1 = As + (256 + tid) * 8;
  short* lB0 = Bs + tid * 8;
  short* lB1 = Bs + (256 + tid) * 8;

  for (int kb = 0; kb < 32; ++kb) {
    __syncthreads();
    glds16(g0, lA0); glds16(g1, lA1);
    glds16(h0, lB0); glds16(h1, lB1);
    g0 += 32; g1 += 32; h0 += 32; h1 += 32;
    __syncthreads();

    v8s a[4], b[4];
#pragma unroll
    for (int mt = 0; mt < 4; ++mt)
      a[mt] = *(const v8s*)(As + (wr + mt * 16 + c15) * 32 + quad * 8);
#pragma unroll
    for (int nt = 0; nt < 4; ++nt)
      b[nt] = *(const v8s*)(Bs + (wc + nt * 16 + c15) * 32 + quad * 8);
#pragma unroll
    for (int mt = 0; mt < 4; ++mt)
#pragma unroll
      for (int nt = 0; nt < 4; ++nt)
        acc[mt][nt] = __builtin_amdgcn_mfma_f32_16x16x32_bf16(a[mt], b[nt], acc[mt][nt], 0, 0, 0);
  }
}

// ---------------- QKV projection ----------------
__global__ __launch_bounds__(256, 2) void proj_gemm(
    const short* __restrict__ xQ, const short* __restrict__ xK, const short* __restrict__ xV,
    const short* __restrict__ WqT, const short* __restrict__ WkT, const short* __restrict__ WvT,
    const float* __restrict__ bq, const float* __restrict__ bk, const float* __restrict__ bv,
    short* __restrict__ Qb, short* __restrict__ Kb, short* __restrict__ Vtb) {
  __shared__ short As[4096];
  __shared__ short Bs[4096];
  const int z = blockIdx.z;
  const short* A    = (z == 0) ? xQ  : (z == 1) ? xK  : xV;
  const short* Bt   = (z == 0) ? WqT : (z == 1) ? WkT : WvT;
  const float* bias = (z == 0) ? bq  : (z == 1) ? bk  : bv;
  short* outp       = (z == 0) ? Qb  : (z == 1) ? Kb  : Vtb;
  const int mb = blockIdx.y * 128, nb = blockIdx.x * 128;
  v4f acc[4][4] = {};
  gemm_core128(A + (size_t)mb * 1024, Bt + (size_t)nb * 1024, As, Bs, acc);

  const int lane = threadIdx.x & 63, w = threadIdx.x >> 6;
  const int quad = lane >> 4, c15 = lane & 15;
  const int wr = (w >> 1) * 64, wc = (w & 1) * 64;
  const bool vmode = (z == 2);
#pragma unroll
  for (int nt = 0; nt < 4; ++nt) {
    const int gn = nb + wc + nt * 16 + c15;
    const float bb = bias[gn];
    const int h = gn >> 6, e = gn & 63;
#pragma unroll
    for (int mt = 0; mt < 4; ++mt) {
#pragma unroll
      for (int r = 0; r < 4; ++r) {
        const int gm = mb + wr + mt * 16 + quad * 4 + r;
        const int bi = gm >> 10, s = gm & 1023;
        const float v = acc[mt][nt][r] + bb;
        const size_t base = (size_t)(bi * 16 + h) * 65536;
        if (!vmode) outp[base + (size_t)s * 64 + e]   = f2bf(v);
        else        outp[base + (size_t)e * 1024 + s] = f2bf(v);
      }
    }
  }
}

// ---------------- output projection ----------------
__global__ __launch_bounds__(256, 2) void out_gemm(
    const short* __restrict__ AV, const short* __restrict__ WoT,
    const float* __restrict__ bo, float* __restrict__ outp) {
  __shared__ short As[4096];
  __shared__ short Bs[4096];
  const int mb = blockIdx.y * 128, nb = blockIdx.x * 128;
  v4f acc[4][4] = {};
  gemm_core128(AV + (size_t)mb * 1024, WoT + (size_t)nb * 1024, As, Bs, acc);
  const int lane = threadIdx.x & 63, w = threadIdx.x >> 6;
  const int quad = lane >> 4, c15 = lane & 15;
  const int wr = (w >> 1) * 64, wc = (w & 1) * 64;
#pragma unroll
  for (int nt = 0; nt < 4; ++nt) {
    const int gn = nb + wc + nt * 16 + c15;
    const float bb = bo[gn];
#pragma unroll
    for (int mt = 0; mt < 4; ++mt)
#pragma unroll
      for (int r = 0; r < 4; ++r) {
        const int gm = mb + wr + mt * 16 + quad * 4 + r;
        outp[(size_t)gm * 1024 + gn] = acc[mt][nt][r] + bb;
      }
  }
}

// ---------------- flash attention (wave-independent, no K/V LDS) ----------------
// grid: 512 flat blocks. XCD swizzle: bh = (flat&7) + 8*((flat>>3)&7) keeps all 8
// q-groups of one (b,h) on one XCD (round-robin dispatch) so K/V stay in its L2.
// Each wave: 32 q-rows (2 m-frags), 16 key-blocks of 64. K/V fragments are 16B-
// contiguous global loads (K=[key][dh], Vt=[dh][key]); LDS only for P transform.
__global__ __launch_bounds__(256, 2) void attn_kernel(
    const short* __restrict__ Qb, const short* __restrict__ Kb,
    const short* __restrict__ Vtb, const int* __restrict__ lens,
    short* __restrict__ AVb) {
  __shared__ short Psm[4 * 32 * 68];   // per-wave [32 rows][64 keys], stride 68 (34 dw)
  const int tid = threadIdx.x, lane = tid & 63, w = tid >> 6;
  const int quad = lane >> 4, c15 = lane & 15;
  const int flat = blockIdx.x;
  const int bh = (flat & 7) + 8 * ((flat >> 3) & 7);
  const int qg = flat >> 6;            // 0..7 : 128-row group
  const int b = bh >> 4, h = bh & 15;
  const short* Qp = Qb  + (size_t)bh * 65536;
  const short* Kp = Kb  + (size_t)bh * 65536;
  const short* Vp = Vtb + (size_t)bh * 65536;
  const int len = lens[b];
  const int row0 = qg * 128 + w * 32;  // this wave's first q row

  // Q A-frags: 2 m-groups x 2 k-halves
  v8s aq[2][2];
#pragma unroll
  for (int mg = 0; mg < 2; ++mg)
#pragma unroll
    for (int kf = 0; kf < 2; ++kf)
      aq[mg][kf] = *(const v8s*)(Qp + (size_t)(row0 + mg * 16 + c15) * 64 + kf * 32 + quad * 8);

  // per-C-row scale: 1/sqrt(64) for live rows, 0 for masked rows (=> p=1 uniform)
  float cs[2][4];
#pragma unroll
  for (int mg = 0; mg < 2; ++mg)
#pragma unroll
    for (int r = 0; r < 4; ++r) {
      int sg = row0 + mg * 16 + quad * 4 + r;
      cs[mg][r] = (sg < len) ? 0.125f : 0.0f;
    }

  float sm[2][4] = {};
  v4f o[2][4] = {};
  short* Pw = Psm + w * (32 * 68);

#pragma unroll 2
  for (int kb = 0; kb < 16; ++kb) {
    const short* kbase = Kp + (size_t)kb * 64 * 64;
    const short* vbase = Vp + kb * 64;

    // K B-frags (shared by both m-groups): K[key=nt*16+c15][dh=kf*32+quad*8+j]
    v8s bk[4][2];
#pragma unroll
    for (int nt = 0; nt < 4; ++nt)
#pragma unroll
      for (int kf = 0; kf < 2; ++kf)
        bk[nt][kf] = *(const v8s*)(kbase + (size_t)(nt * 16 + c15) * 64 + kf * 32 + quad * 8);

    // V B-frags (independent of P; issued early): Vt[dh=t*16+c15][key=kf2*32+quad*8+j]
    v8s bv[4][2];
#pragma unroll
    for (int t = 0; t < 4; ++t)
#pragma unroll
      for (int kf2 = 0; kf2 < 2; ++kf2)
        bv[t][kf2] = *(const v8s*)(vbase + (size_t)(t * 16 + c15) * 1024 + kf2 * 32 + quad * 8);

    // S = Q K^T
    v4f sc[2][4];
#pragma unroll
    for (int mg = 0; mg < 2; ++mg)
#pragma unroll
      for (int nt = 0; nt < 4; ++nt) {
        v4f z = {};
#pragma unroll
        for (int kf = 0; kf < 2; ++kf)
          z = __builtin_amdgcn_mfma_f32_16x16x32_bf16(aq[mg][kf], bk[nt][kf], z, 0, 0, 0);
        sc[mg][nt] = z;
      }

    // fixed-max softmax: p = exp(cs * s); accumulate per-lane partial sums
#pragma unroll
    for (int mg = 0; mg < 2; ++mg)
#pragma unroll
      for (int nt = 0; nt < 4; ++nt)
#pragma unroll
        for (int r = 0; r < 4; ++r) {
          float p = __expf(sc[mg][nt][r] * cs[mg][r]);
          sm[mg][r] += p;
          Pw[(mg * 16 + quad * 4 + r) * 68 + nt * 16 + c15] = f2bf(p);
        }
    __builtin_amdgcn_s_waitcnt(0xc07f);   // lgkmcnt(0); per-wave LDS region

    // O += P V
#pragma unroll
    for (int mg = 0; mg < 2; ++mg)
#pragma unroll
      for (int kf2 = 0; kf2 < 2; ++kf2) {
        v8s pa = *(const v8s*)(Pw + (mg * 16 + c15) * 68 + kf2 * 32 + quad * 8);
#pragma unroll
        for (int t = 0; t < 4; ++t)
          o[mg][t] = __builtin_amdgcn_mfma_f32_16x16x32_bf16(pa, bv[t][kf2], o[mg][t], 0, 0, 0);
      }
  }

  // denominator: reduce partial sums across the 16 lanes of each row group
#pragma unroll
  for (int d = 1; d < 16; d <<= 1)
#pragma unroll
    for (int mg = 0; mg < 2; ++mg)
#pragma unroll
      for (int r = 0; r < 4; ++r) sm[mg][r] += __shfl_xor(sm[mg][r], d);

#pragma unroll
  for (int mg = 0; mg < 2; ++mg) {
    float inv[4];
#pragma unroll
    for (int r = 0; r < 4; ++r) inv[r] = 1.0f / sm[mg][r];
#pragma unroll
    for (int t = 0; t < 4; ++t)
#pragma unroll
      for (int r = 0; r < 4; ++r) {
        int sg = row0 + mg * 16 + quad * 4 + r;
        AVb[(size_t)(b * 1024 + sg) * 1024 + h * 64 + t * 16 + c15] = f2bf(o[mg][t][r] * inv[r]);
      }
  }
}

// ---------------- launch ----------------
extern "C" void kernel_launch(void* const* d_in, const int* in_sizes, int n_in,
                              void* d_out, int out_size, void* d_ws, size_t ws_size,
                              hipStream_t stream) {
  const float* xQ = (const float*)d_in[0];
  const float* xK = (const float*)d_in[1];
  const float* xV = (const float*)d_in[2];
  const int* lens = (const int*)d_in[3];
  const float* Wq = (const float*)d_in[4];
  const float* bq = (const float*)d_in[5];
  const float* Wk = (const float*)d_in[6];
  const float* bk = (const float*)d_in[7];
  const float* Wv = (const float*)d_in[8];
  const float* bv = (const float*)d_in[9];
  const float* Wo = (const float*)d_in[10];
  const float* bo = (const float*)d_in[11];
  float* out = (float*)d_out;

  char* ws = (char*)d_ws;
  short* xQb = (short*)(ws + 0);                 // 8 MB  [4096][1024] bf16
  short* xKb = (short*)(ws + 8388608);
  short* xVb = (short*)(ws + 16777216);
  short* WqT = (short*)(ws + 25165824);          // 2 MB  [n=h*64+e][d]
  short* WkT = (short*)(ws + 27262976);
  short* WvT = (short*)(ws + 29360128);
  short* WoT = (short*)(ws + 31457280);          // 2 MB  Wo^T [n][k]
  short* Qb  = (short*)(ws + 33554432);          // 8 MB  [b,h,s,e]
  short* Kb  = (short*)(ws + 41943040);          // 8 MB  [b,h,s,e]
  short* Vtb = (short*)(ws + 50331648);          // 8 MB  [b,h,e,s]
  short* AVb = (short*)(ws + 58720256);          // 8 MB  [b,s,h*64+e]

  cast3_f32_bf16<<<dim3(4096, 1, 3), 256, 0, stream>>>(xQ, xK, xV, xQb, xKb, xVb, 1048576);
  transpose_cast_w3<<<dim3(16, 1, 48), 256, 0, stream>>>(Wq, Wk, Wv, WqT, WkT, WvT);
  transpose_cast<<<dim3(16, 16, 1), 256, 0, stream>>>(Wo, WoT, 1024, 1024);
  proj_gemm<<<dim3(8, 32, 3), 256, 0, stream>>>(xQb, xKb, xVb, WqT, WkT, WvT,
                                                bq, bk, bv, Qb, Kb, Vtb);
  attn_kernel<<<dim3(512), 256, 0, stream>>>(Qb, Kb, Vtb, lens, AVb);
  out_gemm<<<dim3(8, 32, 1), 256, 0, stream>>>(AVb, WoT, bo, out);
}